// Round 6
// baseline (280.936 us; speedup 1.0000x reference)
//
#include <hip/hip_runtime.h>
#include <hip/hip_bf16.h>

// ---- problem constants ----
constexpr int BB  = 256;   // batch
constexpr int TT  = 1024;  // timesteps
constexpr int DXc = 64;
constexpr int DZc = 128;
constexpr int DBc = 16;
constexpr int TAUc = 25;
constexpr float CLIPV = 10.0f;
constexpr int NF = 40;     // forcing steps: t = 25..1000
constexpr int NSEG = 41;   // independent scan segments (forcing breaks chain)
constexpr int GRP = 16;    // batch rows per scan block (MFMA N dim)

typedef __attribute__((ext_vector_type(8))) short short8;        // 8 bf16
typedef __attribute__((ext_vector_type(8))) _Float16 half8;      // 8 f16
typedef __attribute__((ext_vector_type(4))) float f32x4;
typedef __attribute__((ext_vector_type(4))) unsigned u32x4;
typedef __attribute__((ext_vector_type(2))) unsigned u32x2;

__device__ __forceinline__ unsigned perm_b32(unsigned a, unsigned b, unsigned s) {
  return __builtin_amdgcn_perm(a, b, s);
}

// pack 8 floats into bf16 hi + residual-lo short8 frags (scan kernel)
__device__ __forceinline__ void pack_hilo8(const f32x4 a, const f32x4 b,
                                           short8& hi, short8& lo) {
  float f[8];
  *(f32x4*)&f[0] = a;
  *(f32x4*)&f[4] = b;
  u32x4 hi4, lo4;
  #pragma unroll
  for (int p = 0; p < 4; ++p) {
    const unsigned b0 = __float_as_uint(f[2 * p]);
    const unsigned b1 = __float_as_uint(f[2 * p + 1]);
    hi4[p] = perm_b32(b1, b0, 0x07060302u);
    const float l0 = f[2 * p]     - __uint_as_float(b0 & 0xFFFF0000u);
    const float l1 = f[2 * p + 1] - __uint_as_float(b1 & 0xFFFF0000u);
    lo4[p] = perm_b32(__float_as_uint(l1), __float_as_uint(l0), 0x07060302u);
  }
  hi = __builtin_bit_cast(short8, hi4);
  lo = __builtin_bit_cast(short8, lo4);
}

// 8 floats -> f16 frag (RNE, single precision pass)
__device__ __forceinline__ half8 cvt8_f16(const f32x4 a, const f32x4 b) {
  float f[8];
  *(f32x4*)&f[0] = a;
  *(f32x4*)&f[4] = b;
  u32x4 h4;
  #pragma unroll
  for (int p = 0; p < 4; ++p) {
    const _Float16 h0 = (_Float16)f[2 * p], h1 = (_Float16)f[2 * p + 1];
    h4[p] = (unsigned)__builtin_bit_cast(unsigned short, h0)
          | ((unsigned)__builtin_bit_cast(unsigned short, h1) << 16);
  }
  return __builtin_bit_cast(half8, h4);
}

// 8 floats -> f16 hi + f16 residual frags
__device__ __forceinline__ void cvt8_f16_hilo(const f32x4 a, const f32x4 b,
                                              half8& hi, half8& lo) {
  float f[8];
  *(f32x4*)&f[0] = a;
  *(f32x4*)&f[4] = b;
  u32x4 h4, l4;
  #pragma unroll
  for (int p = 0; p < 4; ++p) {
    const float f0 = f[2 * p], f1 = f[2 * p + 1];
    const _Float16 h0 = (_Float16)f0, h1 = (_Float16)f1;
    const float r0 = f0 - (float)h0, r1 = f1 - (float)h1;
    const _Float16 e0 = (_Float16)r0, e1 = (_Float16)r1;
    h4[p] = (unsigned)__builtin_bit_cast(unsigned short, h0)
          | ((unsigned)__builtin_bit_cast(unsigned short, h1) << 16);
    l4[p] = (unsigned)__builtin_bit_cast(unsigned short, e0)
          | ((unsigned)__builtin_bit_cast(unsigned short, e1) << 16);
  }
  hi = __builtin_bit_cast(half8, h4);
  lo = __builtin_bit_cast(half8, l4);
}

__device__ __forceinline__ unsigned pk2_f16(float a, float b) {
  const _Float16 ha = (_Float16)a, hb = (_Float16)b;
  return (unsigned)__builtin_bit_cast(unsigned short, ha)
       | ((unsigned)__builtin_bit_cast(unsigned short, hb) << 16);
}

// fast tanh: 1 - 2/(1+exp2(2x*log2e)), copysign. ~6 VALU, ~1e-6 rel err.
__device__ __forceinline__ float ftanh(float x) {
  const float ax = __builtin_fabsf(x);
  const float p  = __builtin_amdgcn_exp2f(ax * 2.8853900817779268f);
  const float r  = __builtin_amdgcn_rcpf(p + 1.0f);
  const float t  = __builtin_fmaf(-2.0f, r, 1.0f);
  return __builtin_copysignf(t, x);
}

#define SCAN_BAR() do { \
    __asm__ volatile("s_waitcnt lgkmcnt(0)" ::: "memory"); \
    __builtin_amdgcn_s_barrier(); \
    __asm__ volatile("" ::: "memory"); } while (0)

// =====================================================================
// Fused 2-layer tanh MLP — ENCODER only (40x256 rows). Unchanged.
// =====================================================================
template<int DIN, int DHID, int DOUT, int ROWS, bool GATHER, bool ALIAS>
__global__ __launch_bounds__(256, 1) void mlp_kernel(
    const float* __restrict__ in, const float* __restrict__ w1,
    const float* __restrict__ b1v, const float* __restrict__ w2,
    const float* __restrict__ b2v, float* __restrict__ out)
{
  static_assert(!ALIAS || DIN == DHID, "alias requires DIN==DHID");
  static_assert(DHID == 128, "layer1 tiling assumes DHID==128");
  constexpr int RT = ROWS / 16;
  constexpr int OT = DOUT / 16;

  __shared__ float w1t[DIN * DHID];
  __shared__ float w2t[DHID * DOUT];
  __shared__ float xs[ROWS * DIN];
  __shared__ float ht_sep[ALIAS ? 4 : ROWS * DHID];
  float* htp = ALIAS ? xs : ht_sep;

  const int tid = threadIdx.x;
  const int to = tid & 15, tr = tid >> 4;
  const int row0 = blockIdx.x * ROWS;

  for (int idx = tid; idx < DHID * DIN; idx += 256) {
    const int o = idx / DIN, i = idx - o * DIN;
    w1t[i * DHID + (o ^ ((i & 7) << 2))] = w1[idx];
  }
  for (int idx = tid; idx < DOUT * DHID; idx += 256) {
    const int o = idx / DHID, j = idx - o * DHID;
    w2t[j * DOUT + (o ^ ((j & 7) << 2))] = w2[idx];
  }
  for (int idx = tid; idx < ROWS * DIN; idx += 256) {
    const int r = idx / DIN, i = idx - r * DIN;
    const int rg = row0 + r;
    size_t off;
    if constexpr (GATHER) {
      const int f = rg >> 8, b = rg & 255;
      const int t = TAUc * (f + 1);
      off = ((size_t)b * TT + t) * (size_t)DIN;
    } else {
      off = (size_t)rg * DIN;
    }
    xs[idx] = in[off + i];
  }
  __syncthreads();

  float acc[RT][8];
  #pragma unroll
  for (int a = 0; a < RT; ++a)
    #pragma unroll
    for (int c = 0; c < 8; ++c) acc[a][c] = 0.f;

  for (int i = 0; i < DIN; i += 4) {
    float4 xv[RT];
    #pragma unroll
    for (int a = 0; a < RT; ++a)
      xv[a] = *(const float4*)&xs[(tr * RT + a) * DIN + i];
    #pragma unroll
    for (int ii = 0; ii < 4; ++ii) {
      const int irow = i + ii;
      const int sw = (irow & 7) << 2;
      const float4 wv0 = *(const float4*)&w1t[irow * DHID + ((to * 8 + 0) ^ sw)];
      const float4 wv1 = *(const float4*)&w1t[irow * DHID + ((to * 8 + 4) ^ sw)];
      #pragma unroll
      for (int a = 0; a < RT; ++a) {
        const float xa = reinterpret_cast<const float*>(&xv[a])[ii];
        acc[a][0] = fmaf(xa, wv0.x, acc[a][0]);
        acc[a][1] = fmaf(xa, wv0.y, acc[a][1]);
        acc[a][2] = fmaf(xa, wv0.z, acc[a][2]);
        acc[a][3] = fmaf(xa, wv0.w, acc[a][3]);
        acc[a][4] = fmaf(xa, wv1.x, acc[a][4]);
        acc[a][5] = fmaf(xa, wv1.y, acc[a][5]);
        acc[a][6] = fmaf(xa, wv1.z, acc[a][6]);
        acc[a][7] = fmaf(xa, wv1.w, acc[a][7]);
      }
    }
  }

  __syncthreads();
  #pragma unroll
  for (int a = 0; a < RT; ++a) {
    #pragma unroll
    for (int c4 = 0; c4 < 2; ++c4) {
      float4 hv;
      hv.x = tanhf(acc[a][c4 * 4 + 0] + b1v[to * 8 + c4 * 4 + 0]);
      hv.y = tanhf(acc[a][c4 * 4 + 1] + b1v[to * 8 + c4 * 4 + 1]);
      hv.z = tanhf(acc[a][c4 * 4 + 2] + b1v[to * 8 + c4 * 4 + 2]);
      hv.w = tanhf(acc[a][c4 * 4 + 3] + b1v[to * 8 + c4 * 4 + 3]);
      *(float4*)&htp[(tr * RT + a) * DHID + to * 8 + c4 * 4] = hv;
    }
  }
  __syncthreads();

  float acc2[RT][OT];
  #pragma unroll
  for (int a = 0; a < RT; ++a)
    #pragma unroll
    for (int c = 0; c < OT; ++c) acc2[a][c] = 0.f;

  for (int j = 0; j < DHID; j += 4) {
    float4 hv[RT];
    #pragma unroll
    for (int a = 0; a < RT; ++a)
      hv[a] = *(const float4*)&htp[(tr * RT + a) * DHID + j];
    #pragma unroll
    for (int jj = 0; jj < 4; ++jj) {
      const int jrow = j + jj;
      const int sw = (jrow & 7) << 2;
      #pragma unroll
      for (int c4 = 0; c4 < OT / 4; ++c4) {
        const float4 wv = *(const float4*)&w2t[jrow * DOUT + ((to * OT + c4 * 4) ^ sw)];
        #pragma unroll
        for (int a = 0; a < RT; ++a) {
          const float ha = reinterpret_cast<const float*>(&hv[a])[jj];
          acc2[a][c4 * 4 + 0] = fmaf(ha, wv.x, acc2[a][c4 * 4 + 0]);
          acc2[a][c4 * 4 + 1] = fmaf(ha, wv.y, acc2[a][c4 * 4 + 1]);
          acc2[a][c4 * 4 + 2] = fmaf(ha, wv.z, acc2[a][c4 * 4 + 2]);
          acc2[a][c4 * 4 + 3] = fmaf(ha, wv.w, acc2[a][c4 * 4 + 3]);
        }
      }
    }
  }

  #pragma unroll
  for (int a = 0; a < RT; ++a) {
    const int rg = row0 + tr * RT + a;
    size_t ooff;
    if constexpr (GATHER) {
      const int f = rg >> 8, b = rg & 255;
      const int t = TAUc * (f + 1);
      ooff = ((size_t)b * TT + t) * (size_t)DOUT;
    } else {
      ooff = (size_t)rg * DOUT;
    }
    #pragma unroll
    for (int c4 = 0; c4 < OT / 4; ++c4) {
      float4 ov;
      ov.x = tanhf(acc2[a][c4 * 4 + 0] + b2v[to * OT + c4 * 4 + 0]);
      ov.y = tanhf(acc2[a][c4 * 4 + 1] + b2v[to * OT + c4 * 4 + 1]);
      ov.z = tanhf(acc2[a][c4 * 4 + 2] + b2v[to * OT + c4 * 4 + 2]);
      ov.w = tanhf(acc2[a][c4 * 4 + 3] + b2v[to * OT + c4 * 4 + 3]);
      *(float4*)&out[ooff + to * OT + c4 * 4] = ov;
    }
  }
}

// =====================================================================
// Scan v4 (unchanged, validated): MFMA, 16 batch rows x 41 segments.
// =====================================================================
__global__ __launch_bounds__(256, 1) void scan_mfma_kernel(
    const float* __restrict__ AW, const float* __restrict__ z0,
    const float* __restrict__ hvec, const float* __restrict__ alphas,
    const float* __restrict__ thetas, float* __restrict__ zs)
{
  const int bid = blockIdx.x;
  const int g = bid & 15;
  const int s = bid >> 4;
  const int t0 = s * TAUc;
  const int nsteps = (s == NSEG - 1) ? (TT - t0) : TAUc;

  const int tid = threadIdx.x;
  const int w = tid >> 6, l = tid & 63;
  const int rowf = l & 15;
  const int kg = l >> 4;

  __shared__ float zbuf[DZc][20];
  __shared__ float meanp[16][4];
  __shared__ unsigned pbuf[16][DZc];

  short8 Whi[2][4], Wlo[2][4];
  #pragma unroll
  for (int tm = 0; tm < 2; ++tm) {
    const int m = (2 * w + tm) * 16 + rowf;
    #pragma unroll
    for (int kt = 0; kt < 4; ++kt) {
      const int kb = kt * 32 + kg * 8;
      float f[8];
      #pragma unroll
      for (int i = 0; i < 8; ++i) {
        const int k = kb + i;
        f[i] = (k == m) ? 0.f : AW[m * DZc + k];
      }
      pack_hilo8(*(const f32x4*)&f[0], *(const f32x4*)&f[4],
                 Whi[tm][kt], Wlo[tm][kt]);
    }
  }
  float a_d[2][4], h_d[2][4];
  #pragma unroll
  for (int tm = 0; tm < 2; ++tm)
    #pragma unroll
    for (int j = 0; j < 4; ++j) {
      const int comp = (2 * w + tm) * 16 + kg * 4 + j;
      a_d[tm][j] = AW[comp * DZc + comp];
      h_d[tm][j] = hvec[comp];
    }

  const int cb = tid >> 1;
  const int rh = tid & 1;
  float th[DBc], al[DBc];
  #pragma unroll
  for (int d = 0; d < DBc; ++d) {
    th[d] = thetas[cb * DBc + d];
    al[d] = alphas[d];
  }

  const int brow = g * GRP + rowf;
  const size_t zb_row = (size_t)brow * TT * DZc;
  f32x4 z[2];
  #pragma unroll
  for (int tm = 0; tm < 2; ++tm) {
    const int comp0 = (2 * w + tm) * 16 + kg * 4;
    if (s == 0) z[tm] = *(const f32x4*)&z0[brow * DZc + comp0];
    else        z[tm] = *(const f32x4*)&zs[zb_row + (size_t)t0 * DZc + comp0];
  }

  for (int it = 0; it < nsteps; ++it) {
    const int t = t0 + it;

    float ssum = ((z[0][0] + z[0][1]) + (z[0][2] + z[0][3]))
               + ((z[1][0] + z[1][1]) + (z[1][2] + z[1][3]));
    ssum += __shfl_xor(ssum, 16, 64);
    ssum += __shfl_xor(ssum, 32, 64);
    if (l < 16) meanp[l][w] = ssum;
    #pragma unroll
    for (int tm = 0; tm < 2; ++tm)
      #pragma unroll
      for (int j = 0; j < 4; ++j)
        zbuf[(2 * w + tm) * 16 + kg * 4 + j][rowf] = z[tm][j];
    SCAN_BAR();

    float zr[8], mean[8];
    *(f32x4*)&zr[0] = *(const f32x4*)&zbuf[cb][rh * 8];
    *(f32x4*)&zr[4] = *(const f32x4*)&zbuf[cb][rh * 8 + 4];
    #pragma unroll
    for (int q = 0; q < 8; ++q) {
      const f32x4 mp = *(const f32x4*)&meanp[rh * 8 + q][0];
      mean[q] = ((mp[0] + mp[1]) + (mp[2] + mp[3])) * (1.0f / 128.0f);
    }
    #pragma unroll
    for (int q = 0; q < 8; ++q) {
      const float zc = zr[q] - mean[q];
      float bs = 0.f;
      #pragma unroll
      for (int d = 0; d < DBc; ++d)
        bs = fmaf(al[d], fmaxf(zc + th[d], 0.f), bs);
      const unsigned fb = __float_as_uint(bs);
      const float lof = bs - __uint_as_float(fb & 0xFFFF0000u);
      const unsigned pk = perm_b32(__float_as_uint(lof), fb, 0x07060302u);
      const int r = rh * 8 + q;
      pbuf[r][cb ^ ((r & 3) << 3)] = pk;
    }
    SCAN_BAR();

    f32x4 acc1[2], acc2[2];
    #pragma unroll
    for (int tm = 0; tm < 2; ++tm) {
      #pragma unroll
      for (int j = 0; j < 4; ++j) {
        acc1[tm][j] = fmaf(a_d[tm][j], z[tm][j], h_d[tm][j]);
        acc2[tm][j] = 0.f;
      }
    }
    #pragma unroll
    for (int kt = 0; kt < 4; ++kt) {
      const int cbase = (kt * 32 + kg * 8) ^ ((rowf & 3) << 3);
      const u32x4 p0 = *(const u32x4*)&pbuf[rowf][cbase];
      const u32x4 p1 = *(const u32x4*)&pbuf[rowf][cbase + 4];
      u32x4 hi4, lo4;
      hi4[0] = perm_b32(p0[1], p0[0], 0x05040100u);
      hi4[1] = perm_b32(p0[3], p0[2], 0x05040100u);
      hi4[2] = perm_b32(p1[1], p1[0], 0x05040100u);
      hi4[3] = perm_b32(p1[3], p1[2], 0x05040100u);
      lo4[0] = perm_b32(p0[1], p0[0], 0x07060302u);
      lo4[1] = perm_b32(p0[3], p0[2], 0x07060302u);
      lo4[2] = perm_b32(p1[1], p1[0], 0x07060302u);
      lo4[3] = perm_b32(p1[3], p1[2], 0x07060302u);
      const short8 Bhi = __builtin_bit_cast(short8, hi4);
      const short8 Blo = __builtin_bit_cast(short8, lo4);
      acc1[0] = __builtin_amdgcn_mfma_f32_16x16x32_bf16(Whi[0][kt], Bhi, acc1[0], 0, 0, 0);
      acc1[1] = __builtin_amdgcn_mfma_f32_16x16x32_bf16(Whi[1][kt], Bhi, acc1[1], 0, 0, 0);
      acc2[0] = __builtin_amdgcn_mfma_f32_16x16x32_bf16(Whi[0][kt], Blo, acc2[0], 0, 0, 0);
      acc2[0] = __builtin_amdgcn_mfma_f32_16x16x32_bf16(Wlo[0][kt], Bhi, acc2[0], 0, 0, 0);
      acc2[1] = __builtin_amdgcn_mfma_f32_16x16x32_bf16(Whi[1][kt], Blo, acc2[1], 0, 0, 0);
      acc2[1] = __builtin_amdgcn_mfma_f32_16x16x32_bf16(Wlo[1][kt], Bhi, acc2[1], 0, 0, 0);
    }
    #pragma unroll
    for (int tm = 0; tm < 2; ++tm) {
      f32x4 zn;
      #pragma unroll
      for (int j = 0; j < 4; ++j) {
        float v = acc1[tm][j] + acc2[tm][j];
        zn[j] = fminf(fmaxf(v, -CLIPV), CLIPV);
      }
      *(f32x4*)&zs[zb_row + (size_t)t * DZc + (2 * w + tm) * 16 + kg * 4] = zn;
      z[tm] = zn;
    }
  }
}

// =====================================================================
// Decoder v3: f16 MFMA, single-pass f16 weights (48 VGPR -> truly
// stationary), z in f16 hi+lo. h stored to LDS as packed f16 pairs in
// frag-native order (layer2 B-frag = raw u32x4 read, zero unpack).
// Pair-index XOR swizzle (rowf&7)<<2 => max 2-way conflicts (free).
// z double-buffer prefetch (zPA/zPB named sets) hides global latency
// across the lgkm-only barrier. DEC_NT=8 tiles/block, grid 2048.
// =====================================================================
constexpr int DEC_NT = 8;

__global__ __launch_bounds__(256, 3) void dec_mfma_kernel(
    const float* __restrict__ zs, const float* __restrict__ w1,
    const float* __restrict__ b1v, const float* __restrict__ w2,
    const float* __restrict__ b2v, float* __restrict__ out)
{
  const int tid = threadIdx.x;
  const int w = tid >> 6, l = tid & 63;
  const int rowf = l & 15;                       // MFMA N index (row in tile)
  const int kg = l >> 4;                         // 0..3
  const int g8 = (rowf & 7) << 2;                // pair-index XOR swizzle

  __shared__ unsigned pbuf[2][16][64];           // [buf][row][pair^g8] f16x2

  // ---- stationary f16 weight fragments (32 + 16 VGPRs) ----
  half8 W1f[2][4], W2f[4];
  #pragma unroll
  for (int tm = 0; tm < 2; ++tm) {
    const int m = (2 * w + tm) * 16 + rowf;
    #pragma unroll
    for (int kt = 0; kt < 4; ++kt) {
      const int k0 = kt * 32 + kg * 8;
      W1f[tm][kt] = cvt8_f16(*(const f32x4*)&w1[m * DZc + k0],
                             *(const f32x4*)&w1[m * DZc + k0 + 4]);
    }
  }
  {
    const int m2 = w * 16 + rowf;
    #pragma unroll
    for (int kt = 0; kt < 4; ++kt) {
      const int k0 = kt * 32 + kg * 8;
      W2f[kt] = cvt8_f16(*(const f32x4*)&w2[m2 * DZc + k0],
                         *(const f32x4*)&w2[m2 * DZc + k0 + 4]);
    }
  }
  float b1r[2][4], b2r[4];
  #pragma unroll
  for (int tm = 0; tm < 2; ++tm)
    #pragma unroll
    for (int j = 0; j < 4; ++j)
      b1r[tm][j] = b1v[(2 * w + tm) * 16 + kg * 4 + j];
  #pragma unroll
  for (int j = 0; j < 4; ++j)
    b2r[j] = b2v[w * 16 + kg * 4 + j];

  const int trow0 = blockIdx.x * (DEC_NT * 16);

#define LOADZ(DST, TILE) do { \
    const float* zr_ = zs + (size_t)(trow0 + (TILE) * 16 + rowf) * DZc + kg * 8; \
    _Pragma("unroll") \
    for (int kt = 0; kt < 4; ++kt) { \
      DST[2 * kt]     = *(const f32x4*)&zr_[kt * 32]; \
      DST[2 * kt + 1] = *(const f32x4*)&zr_[kt * 32 + 4]; \
    } } while (0)

#define DEC_BODY(ZC, IT) do { \
    f32x4 acA = {b1r[0][0], b1r[0][1], b1r[0][2], b1r[0][3]}; \
    f32x4 acB = {b1r[1][0], b1r[1][1], b1r[1][2], b1r[1][3]}; \
    _Pragma("unroll") \
    for (int kt = 0; kt < 4; ++kt) { \
      half8 zh, zl; \
      cvt8_f16_hilo(ZC[2 * kt], ZC[2 * kt + 1], zh, zl); \
      acA = __builtin_amdgcn_mfma_f32_16x16x32_f16(W1f[0][kt], zh, acA, 0, 0, 0); \
      acB = __builtin_amdgcn_mfma_f32_16x16x32_f16(W1f[1][kt], zh, acB, 0, 0, 0); \
      acA = __builtin_amdgcn_mfma_f32_16x16x32_f16(W1f[0][kt], zl, acA, 0, 0, 0); \
      acB = __builtin_amdgcn_mfma_f32_16x16x32_f16(W1f[1][kt], zl, acB, 0, 0, 0); \
    } \
    { \
      u32x2 pk0, pk1; \
      pk0[0] = pk2_f16(ftanh(acA[0]), ftanh(acA[1])); \
      pk0[1] = pk2_f16(ftanh(acA[2]), ftanh(acA[3])); \
      pk1[0] = pk2_f16(ftanh(acB[0]), ftanh(acB[1])); \
      pk1[1] = pk2_f16(ftanh(acB[2]), ftanh(acB[3])); \
      const int pA = (2 * w + 0) * 8 + kg * 2; \
      const int pB = (2 * w + 1) * 8 + kg * 2; \
      *(u32x2*)&pbuf[(IT) & 1][rowf][pA ^ g8] = pk0; \
      *(u32x2*)&pbuf[(IT) & 1][rowf][pB ^ g8] = pk1; \
    } \
    SCAN_BAR(); \
    { \
      f32x4 a2 = {b2r[0], b2r[1], b2r[2], b2r[3]}; \
      _Pragma("unroll") \
      for (int kt = 0; kt < 4; ++kt) { \
        const u32x4 hp = *(const u32x4*)&pbuf[(IT) & 1][rowf][(kt * 16 + kg * 4) ^ g8]; \
        a2 = __builtin_amdgcn_mfma_f32_16x16x32_f16(W2f[kt], __builtin_bit_cast(half8, hp), a2, 0, 0, 0); \
      } \
      f32x4 ov; \
      _Pragma("unroll") \
      for (int j = 0; j < 4; ++j) ov[j] = ftanh(a2[j]); \
      *(f32x4*)&out[(size_t)(trow0 + (IT) * 16 + rowf) * DXc + w * 16 + kg * 4] = ov; \
    } } while (0)

  f32x4 zPA[8], zPB[8];
  LOADZ(zPA, 0);
  for (int it = 0; it < DEC_NT; it += 2) {
    LOADZ(zPB, it + 1);
    DEC_BODY(zPA, it);
    const int t2 = (it + 2 < DEC_NT) ? (it + 2) : (DEC_NT - 1);
    LOADZ(zPA, t2);
    DEC_BODY(zPB, it + 1);
  }
#undef LOADZ
#undef DEC_BODY
}

extern "C" void kernel_launch(void* const* d_in, const int* in_sizes, int n_in,
                              void* d_out, int out_size, void* d_ws, size_t ws_size,
                              hipStream_t stream) {
  const float* x      = (const float*)d_in[0];
  const float* z0     = (const float*)d_in[1];
  const float* AW     = (const float*)d_in[2];
  const float* hvec   = (const float*)d_in[3];
  const float* alphas = (const float*)d_in[4];
  const float* thetas = (const float*)d_in[5];
  const float* ew1    = (const float*)d_in[6];
  const float* eb1    = (const float*)d_in[7];
  const float* ew2    = (const float*)d_in[8];
  const float* eb2    = (const float*)d_in[9];
  const float* dw1    = (const float*)d_in[10];
  const float* db1    = (const float*)d_in[11];
  const float* dw2    = (const float*)d_in[12];
  const float* db2    = (const float*)d_in[13];

  float* xp = (float*)d_out;                       // (B,T,DX)
  float* zs = xp + (size_t)BB * TT * DXc;          // (B,T,DZ)

  // 1) encoder at the 40 forcing timesteps -> stash into zs slots
  hipLaunchKernelGGL((mlp_kernel<DXc, DZc, DZc, 32, true, false>),
                     dim3(NF * BB / 32), dim3(256), 0, stream,
                     x, ew1, eb1, ew2, eb2, zs);

  // 2) recurrence scan: MFMA, 16-row groups x 41 segments
  hipLaunchKernelGGL(scan_mfma_kernel, dim3((BB / GRP) * NSEG), dim3(256), 0, stream,
                     AW, z0, hvec, alphas, thetas, zs);

  // 3) decoder: f16 MFMA, weights-stationary, z-prefetch pipeline
  hipLaunchKernelGGL(dec_mfma_kernel, dim3(BB * TT / (DEC_NT * 16)), dim3(256), 0, stream,
                     zs, dw1, db1, dw2, db2, xp);
}

// Round 7
// 237.962 us; speedup vs baseline: 1.1806x; 1.1806x over previous
//
#include <hip/hip_runtime.h>
#include <hip/hip_bf16.h>

// ---- problem constants ----
constexpr int BB  = 256;   // batch
constexpr int TT  = 1024;  // timesteps
constexpr int DXc = 64;
constexpr int DZc = 128;
constexpr int DBc = 16;
constexpr int TAUc = 25;
constexpr float CLIPV = 10.0f;
constexpr int NF = 40;     // forcing steps: t = 25..1000
constexpr int NSEG = 41;   // independent scan segments (forcing breaks chain)
constexpr int GRP = 16;    // batch rows per scan block (MFMA N dim)

typedef __attribute__((ext_vector_type(8))) short short8;        // 8 bf16
typedef __attribute__((ext_vector_type(8))) _Float16 half8;      // 8 f16
typedef __attribute__((ext_vector_type(4))) float f32x4;
typedef __attribute__((ext_vector_type(4))) unsigned u32x4;
typedef __attribute__((ext_vector_type(2))) unsigned u32x2;

__device__ __forceinline__ unsigned perm_b32(unsigned a, unsigned b, unsigned s) {
  return __builtin_amdgcn_perm(a, b, s);
}

// pack 8 floats into bf16 hi + residual-lo short8 frags (scan kernel)
__device__ __forceinline__ void pack_hilo8(const f32x4 a, const f32x4 b,
                                           short8& hi, short8& lo) {
  float f[8];
  *(f32x4*)&f[0] = a;
  *(f32x4*)&f[4] = b;
  u32x4 hi4, lo4;
  #pragma unroll
  for (int p = 0; p < 4; ++p) {
    const unsigned b0 = __float_as_uint(f[2 * p]);
    const unsigned b1 = __float_as_uint(f[2 * p + 1]);
    hi4[p] = perm_b32(b1, b0, 0x07060302u);
    const float l0 = f[2 * p]     - __uint_as_float(b0 & 0xFFFF0000u);
    const float l1 = f[2 * p + 1] - __uint_as_float(b1 & 0xFFFF0000u);
    lo4[p] = perm_b32(__float_as_uint(l1), __float_as_uint(l0), 0x07060302u);
  }
  hi = __builtin_bit_cast(short8, hi4);
  lo = __builtin_bit_cast(short8, lo4);
}

// 8 floats -> f16 frag (RNE, single precision pass)
__device__ __forceinline__ half8 cvt8_f16(const f32x4 a, const f32x4 b) {
  float f[8];
  *(f32x4*)&f[0] = a;
  *(f32x4*)&f[4] = b;
  u32x4 h4;
  #pragma unroll
  for (int p = 0; p < 4; ++p) {
    const _Float16 h0 = (_Float16)f[2 * p], h1 = (_Float16)f[2 * p + 1];
    h4[p] = (unsigned)__builtin_bit_cast(unsigned short, h0)
          | ((unsigned)__builtin_bit_cast(unsigned short, h1) << 16);
  }
  return __builtin_bit_cast(half8, h4);
}

// 8 floats -> f16 hi + f16 residual frags
__device__ __forceinline__ void cvt8_f16_hilo(const f32x4 a, const f32x4 b,
                                              half8& hi, half8& lo) {
  float f[8];
  *(f32x4*)&f[0] = a;
  *(f32x4*)&f[4] = b;
  u32x4 h4, l4;
  #pragma unroll
  for (int p = 0; p < 4; ++p) {
    const float f0 = f[2 * p], f1 = f[2 * p + 1];
    const _Float16 h0 = (_Float16)f0, h1 = (_Float16)f1;
    const float r0 = f0 - (float)h0, r1 = f1 - (float)h1;
    const _Float16 e0 = (_Float16)r0, e1 = (_Float16)r1;
    h4[p] = (unsigned)__builtin_bit_cast(unsigned short, h0)
          | ((unsigned)__builtin_bit_cast(unsigned short, h1) << 16);
    l4[p] = (unsigned)__builtin_bit_cast(unsigned short, e0)
          | ((unsigned)__builtin_bit_cast(unsigned short, e1) << 16);
  }
  hi = __builtin_bit_cast(half8, h4);
  lo = __builtin_bit_cast(half8, l4);
}

__device__ __forceinline__ unsigned pk2_f16(float a, float b) {
  const _Float16 ha = (_Float16)a, hb = (_Float16)b;
  return (unsigned)__builtin_bit_cast(unsigned short, ha)
       | ((unsigned)__builtin_bit_cast(unsigned short, hb) << 16);
}

// fast tanh: 1 - 2/(1+exp2(2x*log2e)), copysign. ~6 VALU, ~1e-6 rel err.
__device__ __forceinline__ float ftanh(float x) {
  const float ax = __builtin_fabsf(x);
  const float p  = __builtin_amdgcn_exp2f(ax * 2.8853900817779268f);
  const float r  = __builtin_amdgcn_rcpf(p + 1.0f);
  const float t  = __builtin_fmaf(-2.0f, r, 1.0f);
  return __builtin_copysignf(t, x);
}

#define SCAN_BAR() do { \
    __asm__ volatile("s_waitcnt lgkmcnt(0)" ::: "memory"); \
    __builtin_amdgcn_s_barrier(); \
    __asm__ volatile("" ::: "memory"); } while (0)

// =====================================================================
// Fused 2-layer tanh MLP — ENCODER only (40x256 rows). Unchanged.
// =====================================================================
template<int DIN, int DHID, int DOUT, int ROWS, bool GATHER, bool ALIAS>
__global__ __launch_bounds__(256, 1) void mlp_kernel(
    const float* __restrict__ in, const float* __restrict__ w1,
    const float* __restrict__ b1v, const float* __restrict__ w2,
    const float* __restrict__ b2v, float* __restrict__ out)
{
  static_assert(!ALIAS || DIN == DHID, "alias requires DIN==DHID");
  static_assert(DHID == 128, "layer1 tiling assumes DHID==128");
  constexpr int RT = ROWS / 16;
  constexpr int OT = DOUT / 16;

  __shared__ float w1t[DIN * DHID];
  __shared__ float w2t[DHID * DOUT];
  __shared__ float xs[ROWS * DIN];
  __shared__ float ht_sep[ALIAS ? 4 : ROWS * DHID];
  float* htp = ALIAS ? xs : ht_sep;

  const int tid = threadIdx.x;
  const int to = tid & 15, tr = tid >> 4;
  const int row0 = blockIdx.x * ROWS;

  for (int idx = tid; idx < DHID * DIN; idx += 256) {
    const int o = idx / DIN, i = idx - o * DIN;
    w1t[i * DHID + (o ^ ((i & 7) << 2))] = w1[idx];
  }
  for (int idx = tid; idx < DOUT * DHID; idx += 256) {
    const int o = idx / DHID, j = idx - o * DHID;
    w2t[j * DOUT + (o ^ ((j & 7) << 2))] = w2[idx];
  }
  for (int idx = tid; idx < ROWS * DIN; idx += 256) {
    const int r = idx / DIN, i = idx - r * DIN;
    const int rg = row0 + r;
    size_t off;
    if constexpr (GATHER) {
      const int f = rg >> 8, b = rg & 255;
      const int t = TAUc * (f + 1);
      off = ((size_t)b * TT + t) * (size_t)DIN;
    } else {
      off = (size_t)rg * DIN;
    }
    xs[idx] = in[off + i];
  }
  __syncthreads();

  float acc[RT][8];
  #pragma unroll
  for (int a = 0; a < RT; ++a)
    #pragma unroll
    for (int c = 0; c < 8; ++c) acc[a][c] = 0.f;

  for (int i = 0; i < DIN; i += 4) {
    float4 xv[RT];
    #pragma unroll
    for (int a = 0; a < RT; ++a)
      xv[a] = *(const float4*)&xs[(tr * RT + a) * DIN + i];
    #pragma unroll
    for (int ii = 0; ii < 4; ++ii) {
      const int irow = i + ii;
      const int sw = (irow & 7) << 2;
      const float4 wv0 = *(const float4*)&w1t[irow * DHID + ((to * 8 + 0) ^ sw)];
      const float4 wv1 = *(const float4*)&w1t[irow * DHID + ((to * 8 + 4) ^ sw)];
      #pragma unroll
      for (int a = 0; a < RT; ++a) {
        const float xa = reinterpret_cast<const float*>(&xv[a])[ii];
        acc[a][0] = fmaf(xa, wv0.x, acc[a][0]);
        acc[a][1] = fmaf(xa, wv0.y, acc[a][1]);
        acc[a][2] = fmaf(xa, wv0.z, acc[a][2]);
        acc[a][3] = fmaf(xa, wv0.w, acc[a][3]);
        acc[a][4] = fmaf(xa, wv1.x, acc[a][4]);
        acc[a][5] = fmaf(xa, wv1.y, acc[a][5]);
        acc[a][6] = fmaf(xa, wv1.z, acc[a][6]);
        acc[a][7] = fmaf(xa, wv1.w, acc[a][7]);
      }
    }
  }

  __syncthreads();
  #pragma unroll
  for (int a = 0; a < RT; ++a) {
    #pragma unroll
    for (int c4 = 0; c4 < 2; ++c4) {
      float4 hv;
      hv.x = tanhf(acc[a][c4 * 4 + 0] + b1v[to * 8 + c4 * 4 + 0]);
      hv.y = tanhf(acc[a][c4 * 4 + 1] + b1v[to * 8 + c4 * 4 + 1]);
      hv.z = tanhf(acc[a][c4 * 4 + 2] + b1v[to * 8 + c4 * 4 + 2]);
      hv.w = tanhf(acc[a][c4 * 4 + 3] + b1v[to * 8 + c4 * 4 + 3]);
      *(float4*)&htp[(tr * RT + a) * DHID + to * 8 + c4 * 4] = hv;
    }
  }
  __syncthreads();

  float acc2[RT][OT];
  #pragma unroll
  for (int a = 0; a < RT; ++a)
    #pragma unroll
    for (int c = 0; c < OT; ++c) acc2[a][c] = 0.f;

  for (int j = 0; j < DHID; j += 4) {
    float4 hv[RT];
    #pragma unroll
    for (int a = 0; a < RT; ++a)
      hv[a] = *(const float4*)&htp[(tr * RT + a) * DHID + j];
    #pragma unroll
    for (int jj = 0; jj < 4; ++jj) {
      const int jrow = j + jj;
      const int sw = (jrow & 7) << 2;
      #pragma unroll
      for (int c4 = 0; c4 < OT / 4; ++c4) {
        const float4 wv = *(const float4*)&w2t[jrow * DOUT + ((to * OT + c4 * 4) ^ sw)];
        #pragma unroll
        for (int a = 0; a < RT; ++a) {
          const float ha = reinterpret_cast<const float*>(&hv[a])[jj];
          acc2[a][c4 * 4 + 0] = fmaf(ha, wv.x, acc2[a][c4 * 4 + 0]);
          acc2[a][c4 * 4 + 1] = fmaf(ha, wv.y, acc2[a][c4 * 4 + 1]);
          acc2[a][c4 * 4 + 2] = fmaf(ha, wv.z, acc2[a][c4 * 4 + 2]);
          acc2[a][c4 * 4 + 3] = fmaf(ha, wv.w, acc2[a][c4 * 4 + 3]);
        }
      }
    }
  }

  #pragma unroll
  for (int a = 0; a < RT; ++a) {
    const int rg = row0 + tr * RT + a;
    size_t ooff;
    if constexpr (GATHER) {
      const int f = rg >> 8, b = rg & 255;
      const int t = TAUc * (f + 1);
      ooff = ((size_t)b * TT + t) * (size_t)DOUT;
    } else {
      ooff = (size_t)rg * DOUT;
    }
    #pragma unroll
    for (int c4 = 0; c4 < OT / 4; ++c4) {
      float4 ov;
      ov.x = tanhf(acc2[a][c4 * 4 + 0] + b2v[to * OT + c4 * 4 + 0]);
      ov.y = tanhf(acc2[a][c4 * 4 + 1] + b2v[to * OT + c4 * 4 + 1]);
      ov.z = tanhf(acc2[a][c4 * 4 + 2] + b2v[to * OT + c4 * 4 + 2]);
      ov.w = tanhf(acc2[a][c4 * 4 + 3] + b2v[to * OT + c4 * 4 + 3]);
      *(float4*)&out[ooff + to * OT + c4 * 4] = ov;
    }
  }
}

// =====================================================================
// Scan v5: as v4 (validated math) but pbuf row pitch padded 128 -> 132
// words. Old layout: pitch 128 == 0 mod 32 banks, so all 16 rows
// aliased and the u32x4 B-frag read was a 16-way conflict (the XOR
// swizzle only toggled bits 3-4, useless). Pitch 132 => bank =
// (4*rowf + off) & 31: write 2-way (free), read ~2x min. XOR removed
// (identity both sides).
// =====================================================================
__global__ __launch_bounds__(256, 1) void scan_mfma_kernel(
    const float* __restrict__ AW, const float* __restrict__ z0,
    const float* __restrict__ hvec, const float* __restrict__ alphas,
    const float* __restrict__ thetas, float* __restrict__ zs)
{
  const int bid = blockIdx.x;
  const int g = bid & 15;
  const int s = bid >> 4;
  const int t0 = s * TAUc;
  const int nsteps = (s == NSEG - 1) ? (TT - t0) : TAUc;

  const int tid = threadIdx.x;
  const int w = tid >> 6, l = tid & 63;
  const int rowf = l & 15;
  const int kg = l >> 4;

  __shared__ float zbuf[DZc][20];
  __shared__ float meanp[16][4];
  __shared__ unsigned pbuf[16][DZc + 4];   // pitch 132: bank=(4*row+off)&31

  short8 Whi[2][4], Wlo[2][4];
  #pragma unroll
  for (int tm = 0; tm < 2; ++tm) {
    const int m = (2 * w + tm) * 16 + rowf;
    #pragma unroll
    for (int kt = 0; kt < 4; ++kt) {
      const int kb = kt * 32 + kg * 8;
      float f[8];
      #pragma unroll
      for (int i = 0; i < 8; ++i) {
        const int k = kb + i;
        f[i] = (k == m) ? 0.f : AW[m * DZc + k];
      }
      pack_hilo8(*(const f32x4*)&f[0], *(const f32x4*)&f[4],
                 Whi[tm][kt], Wlo[tm][kt]);
    }
  }
  float a_d[2][4], h_d[2][4];
  #pragma unroll
  for (int tm = 0; tm < 2; ++tm)
    #pragma unroll
    for (int j = 0; j < 4; ++j) {
      const int comp = (2 * w + tm) * 16 + kg * 4 + j;
      a_d[tm][j] = AW[comp * DZc + comp];
      h_d[tm][j] = hvec[comp];
    }

  const int cb = tid >> 1;
  const int rh = tid & 1;
  float th[DBc], al[DBc];
  #pragma unroll
  for (int d = 0; d < DBc; ++d) {
    th[d] = thetas[cb * DBc + d];
    al[d] = alphas[d];
  }

  const int brow = g * GRP + rowf;
  const size_t zb_row = (size_t)brow * TT * DZc;
  f32x4 z[2];
  #pragma unroll
  for (int tm = 0; tm < 2; ++tm) {
    const int comp0 = (2 * w + tm) * 16 + kg * 4;
    if (s == 0) z[tm] = *(const f32x4*)&z0[brow * DZc + comp0];
    else        z[tm] = *(const f32x4*)&zs[zb_row + (size_t)t0 * DZc + comp0];
  }

  for (int it = 0; it < nsteps; ++it) {
    const int t = t0 + it;

    float ssum = ((z[0][0] + z[0][1]) + (z[0][2] + z[0][3]))
               + ((z[1][0] + z[1][1]) + (z[1][2] + z[1][3]));
    ssum += __shfl_xor(ssum, 16, 64);
    ssum += __shfl_xor(ssum, 32, 64);
    if (l < 16) meanp[l][w] = ssum;
    #pragma unroll
    for (int tm = 0; tm < 2; ++tm)
      #pragma unroll
      for (int j = 0; j < 4; ++j)
        zbuf[(2 * w + tm) * 16 + kg * 4 + j][rowf] = z[tm][j];
    SCAN_BAR();

    float zr[8], mean[8];
    *(f32x4*)&zr[0] = *(const f32x4*)&zbuf[cb][rh * 8];
    *(f32x4*)&zr[4] = *(const f32x4*)&zbuf[cb][rh * 8 + 4];
    #pragma unroll
    for (int q = 0; q < 8; ++q) {
      const f32x4 mp = *(const f32x4*)&meanp[rh * 8 + q][0];
      mean[q] = ((mp[0] + mp[1]) + (mp[2] + mp[3])) * (1.0f / 128.0f);
    }
    #pragma unroll
    for (int q = 0; q < 8; ++q) {
      const float zc = zr[q] - mean[q];
      float bs = 0.f;
      #pragma unroll
      for (int d = 0; d < DBc; ++d)
        bs = fmaf(al[d], fmaxf(zc + th[d], 0.f), bs);
      const unsigned fb = __float_as_uint(bs);
      const float lof = bs - __uint_as_float(fb & 0xFFFF0000u);
      const unsigned pk = perm_b32(__float_as_uint(lof), fb, 0x07060302u);
      const int r = rh * 8 + q;
      pbuf[r][cb] = pk;                       // 2-way max (pitch 132)
    }
    SCAN_BAR();

    f32x4 acc1[2], acc2[2];
    #pragma unroll
    for (int tm = 0; tm < 2; ++tm) {
      #pragma unroll
      for (int j = 0; j < 4; ++j) {
        acc1[tm][j] = fmaf(a_d[tm][j], z[tm][j], h_d[tm][j]);
        acc2[tm][j] = 0.f;
      }
    }
    #pragma unroll
    for (int kt = 0; kt < 4; ++kt) {
      const int cbase = kt * 32 + kg * 8;
      const u32x4 p0 = *(const u32x4*)&pbuf[rowf][cbase];
      const u32x4 p1 = *(const u32x4*)&pbuf[rowf][cbase + 4];
      u32x4 hi4, lo4;
      hi4[0] = perm_b32(p0[1], p0[0], 0x05040100u);
      hi4[1] = perm_b32(p0[3], p0[2], 0x05040100u);
      hi4[2] = perm_b32(p1[1], p1[0], 0x05040100u);
      hi4[3] = perm_b32(p1[3], p1[2], 0x05040100u);
      lo4[0] = perm_b32(p0[1], p0[0], 0x07060302u);
      lo4[1] = perm_b32(p0[3], p0[2], 0x07060302u);
      lo4[2] = perm_b32(p1[1], p1[0], 0x07060302u);
      lo4[3] = perm_b32(p1[3], p1[2], 0x07060302u);
      const short8 Bhi = __builtin_bit_cast(short8, hi4);
      const short8 Blo = __builtin_bit_cast(short8, lo4);
      acc1[0] = __builtin_amdgcn_mfma_f32_16x16x32_bf16(Whi[0][kt], Bhi, acc1[0], 0, 0, 0);
      acc1[1] = __builtin_amdgcn_mfma_f32_16x16x32_bf16(Whi[1][kt], Bhi, acc1[1], 0, 0, 0);
      acc2[0] = __builtin_amdgcn_mfma_f32_16x16x32_bf16(Whi[0][kt], Blo, acc2[0], 0, 0, 0);
      acc2[0] = __builtin_amdgcn_mfma_f32_16x16x32_bf16(Wlo[0][kt], Bhi, acc2[0], 0, 0, 0);
      acc2[1] = __builtin_amdgcn_mfma_f32_16x16x32_bf16(Whi[1][kt], Blo, acc2[1], 0, 0, 0);
      acc2[1] = __builtin_amdgcn_mfma_f32_16x16x32_bf16(Wlo[1][kt], Bhi, acc2[1], 0, 0, 0);
    }
    #pragma unroll
    for (int tm = 0; tm < 2; ++tm) {
      f32x4 zn;
      #pragma unroll
      for (int j = 0; j < 4; ++j) {
        float v = acc1[tm][j] + acc2[tm][j];
        zn[j] = fminf(fmaxf(v, -CLIPV), CLIPV);
      }
      *(f32x4*)&zs[zb_row + (size_t)t * DZc + (2 * w + tm) * 16 + kg * 4] = zn;
      z[tm] = zn;
    }
  }
}

// =====================================================================
// Decoder v4: R5 loop structure (direct z loads in the kt loop, NO
// register prefetch buffers -> no scratch spill), R6's cheaper math
// (f16 single-pass weights = 48 VGPR, z in f16 hi+lo, 20 MFMA/tile),
// and the bank-alias fix: pbuf [2][16][68] u32 (pitch 68 == 4 mod 32,
// writes 2-way, reads ~2x min). DEC_NT=4 tiles/block, grid 4096.
// =====================================================================
constexpr int DEC_NT = 4;

__global__ __launch_bounds__(256, 3) void dec_mfma_kernel(
    const float* __restrict__ zs, const float* __restrict__ w1,
    const float* __restrict__ b1v, const float* __restrict__ w2,
    const float* __restrict__ b2v, float* __restrict__ out)
{
  const int tid = threadIdx.x;
  const int w = tid >> 6, l = tid & 63;
  const int rowf = l & 15;                       // MFMA N index (row in tile)
  const int kg = l >> 4;                         // 0..3

  __shared__ unsigned pbuf[2][16][68];           // [buf][row][pair] f16x2, pitch 68

  // ---- stationary f16 weight fragments (32 + 16 VGPRs) ----
  half8 W1f[2][4], W2f[4];
  #pragma unroll
  for (int tm = 0; tm < 2; ++tm) {
    const int m = (2 * w + tm) * 16 + rowf;
    #pragma unroll
    for (int kt = 0; kt < 4; ++kt) {
      const int k0 = kt * 32 + kg * 8;
      W1f[tm][kt] = cvt8_f16(*(const f32x4*)&w1[m * DZc + k0],
                             *(const f32x4*)&w1[m * DZc + k0 + 4]);
    }
  }
  {
    const int m2 = w * 16 + rowf;
    #pragma unroll
    for (int kt = 0; kt < 4; ++kt) {
      const int k0 = kt * 32 + kg * 8;
      W2f[kt] = cvt8_f16(*(const f32x4*)&w2[m2 * DZc + k0],
                         *(const f32x4*)&w2[m2 * DZc + k0 + 4]);
    }
  }
  float b1r[2][4], b2r[4];
  #pragma unroll
  for (int tm = 0; tm < 2; ++tm)
    #pragma unroll
    for (int j = 0; j < 4; ++j)
      b1r[tm][j] = b1v[(2 * w + tm) * 16 + kg * 4 + j];
  #pragma unroll
  for (int j = 0; j < 4; ++j)
    b2r[j] = b2v[w * 16 + kg * 4 + j];

  const int trow0 = blockIdx.x * (DEC_NT * 16);

  for (int it = 0; it < DEC_NT; ++it) {
    const int grow = trow0 + it * 16 + rowf;
    const float* zrow = zs + (size_t)grow * DZc + kg * 8;

    // ---- layer 1: h = W1 @ z^T + b1 (z in f16 hi+lo) ----
    f32x4 acA = {b1r[0][0], b1r[0][1], b1r[0][2], b1r[0][3]};
    f32x4 acB = {b1r[1][0], b1r[1][1], b1r[1][2], b1r[1][3]};
    #pragma unroll
    for (int kt = 0; kt < 4; ++kt) {
      const f32x4 za = *(const f32x4*)&zrow[kt * 32];
      const f32x4 zb = *(const f32x4*)&zrow[kt * 32 + 4];
      half8 zh, zl;
      cvt8_f16_hilo(za, zb, zh, zl);
      acA = __builtin_amdgcn_mfma_f32_16x16x32_f16(W1f[0][kt], zh, acA, 0, 0, 0);
      acB = __builtin_amdgcn_mfma_f32_16x16x32_f16(W1f[1][kt], zh, acB, 0, 0, 0);
      acA = __builtin_amdgcn_mfma_f32_16x16x32_f16(W1f[0][kt], zl, acA, 0, 0, 0);
      acB = __builtin_amdgcn_mfma_f32_16x16x32_f16(W1f[1][kt], zl, acB, 0, 0, 0);
    }

    // ---- tanh + pack h pairs into LDS (frag-native order) ----
    {
      u32x2 pk0, pk1;
      pk0[0] = pk2_f16(ftanh(acA[0]), ftanh(acA[1]));
      pk0[1] = pk2_f16(ftanh(acA[2]), ftanh(acA[3]));
      pk1[0] = pk2_f16(ftanh(acB[0]), ftanh(acB[1]));
      pk1[1] = pk2_f16(ftanh(acB[2]), ftanh(acB[3]));
      *(u32x2*)&pbuf[it & 1][rowf][(2 * w + 0) * 8 + kg * 2] = pk0;
      *(u32x2*)&pbuf[it & 1][rowf][(2 * w + 1) * 8 + kg * 2] = pk1;
    }
    SCAN_BAR();

    // ---- layer 2: x = W2 @ h^T + b2 (B-frag = raw u32x4 read) ----
    {
      f32x4 a2 = {b2r[0], b2r[1], b2r[2], b2r[3]};
      #pragma unroll
      for (int kt = 0; kt < 4; ++kt) {
        const u32x4 hp = *(const u32x4*)&pbuf[it & 1][rowf][kt * 16 + kg * 4];
        a2 = __builtin_amdgcn_mfma_f32_16x16x32_f16(W2f[kt], __builtin_bit_cast(half8, hp), a2, 0, 0, 0);
      }
      f32x4 ov;
      #pragma unroll
      for (int j = 0; j < 4; ++j) ov[j] = ftanh(a2[j]);
      *(f32x4*)&out[(size_t)grow * DXc + w * 16 + kg * 4] = ov;
    }
  }
}

extern "C" void kernel_launch(void* const* d_in, const int* in_sizes, int n_in,
                              void* d_out, int out_size, void* d_ws, size_t ws_size,
                              hipStream_t stream) {
  const float* x      = (const float*)d_in[0];
  const float* z0     = (const float*)d_in[1];
  const float* AW     = (const float*)d_in[2];
  const float* hvec   = (const float*)d_in[3];
  const float* alphas = (const float*)d_in[4];
  const float* thetas = (const float*)d_in[5];
  const float* ew1    = (const float*)d_in[6];
  const float* eb1    = (const float*)d_in[7];
  const float* ew2    = (const float*)d_in[8];
  const float* eb2    = (const float*)d_in[9];
  const float* dw1    = (const float*)d_in[10];
  const float* db1    = (const float*)d_in[11];
  const float* dw2    = (const float*)d_in[12];
  const float* db2    = (const float*)d_in[13];

  float* xp = (float*)d_out;                       // (B,T,DX)
  float* zs = xp + (size_t)BB * TT * DXc;          // (B,T,DZ)

  // 1) encoder at the 40 forcing timesteps -> stash into zs slots
  hipLaunchKernelGGL((mlp_kernel<DXc, DZc, DZc, 32, true, false>),
                     dim3(NF * BB / 32), dim3(256), 0, stream,
                     x, ew1, eb1, ew2, eb2, zs);

  // 2) recurrence scan: MFMA, 16-row groups x 41 segments
  hipLaunchKernelGGL(scan_mfma_kernel, dim3((BB / GRP) * NSEG), dim3(256), 0, stream,
                     AW, z0, hvec, alphas, thetas, zs);

  // 3) decoder: f16 MFMA, weights-stationary, no reg-prefetch (v4)
  hipLaunchKernelGGL(dec_mfma_kernel, dim3(BB * TT / (DEC_NT * 16)), dim3(256), 0, stream,
                     zs, dw1, db1, dw2, db2, xp);
}

// Round 8
// 156.334 us; speedup vs baseline: 1.7970x; 1.5221x over previous
//
#include <hip/hip_runtime.h>
#include <hip/hip_bf16.h>

// ---- problem constants ----
constexpr int BB  = 256;   // batch
constexpr int TT  = 1024;  // timesteps
constexpr int DXc = 64;
constexpr int DZc = 128;
constexpr int DBc = 16;
constexpr int TAUc = 25;
constexpr float CLIPV = 10.0f;
constexpr int NF = 40;     // forcing steps: t = 25..1000
constexpr int NSEG = 41;   // independent scan segments (forcing breaks chain)
constexpr int GRP = 16;    // batch rows per scan block (MFMA N dim)

typedef __attribute__((ext_vector_type(8))) short short8;        // 8 bf16
typedef __attribute__((ext_vector_type(8))) _Float16 half8;      // 8 f16
typedef __attribute__((ext_vector_type(4))) float f32x4;
typedef __attribute__((ext_vector_type(4))) unsigned u32x4;
typedef __attribute__((ext_vector_type(2))) unsigned u32x2;

__device__ __forceinline__ unsigned perm_b32(unsigned a, unsigned b, unsigned s) {
  return __builtin_amdgcn_perm(a, b, s);
}

// pack 8 floats into bf16 hi + residual-lo short8 frags (scan recurrence)
__device__ __forceinline__ void pack_hilo8(const f32x4 a, const f32x4 b,
                                           short8& hi, short8& lo) {
  float f[8];
  *(f32x4*)&f[0] = a;
  *(f32x4*)&f[4] = b;
  u32x4 hi4, lo4;
  #pragma unroll
  for (int p = 0; p < 4; ++p) {
    const unsigned b0 = __float_as_uint(f[2 * p]);
    const unsigned b1 = __float_as_uint(f[2 * p + 1]);
    hi4[p] = perm_b32(b1, b0, 0x07060302u);
    const float l0 = f[2 * p]     - __uint_as_float(b0 & 0xFFFF0000u);
    const float l1 = f[2 * p + 1] - __uint_as_float(b1 & 0xFFFF0000u);
    lo4[p] = perm_b32(__float_as_uint(l1), __float_as_uint(l0), 0x07060302u);
  }
  hi = __builtin_bit_cast(short8, hi4);
  lo = __builtin_bit_cast(short8, lo4);
}

// 8 floats -> f16 frag (RNE, single precision pass)
__device__ __forceinline__ half8 cvt8_f16(const f32x4 a, const f32x4 b) {
  float f[8];
  *(f32x4*)&f[0] = a;
  *(f32x4*)&f[4] = b;
  u32x4 h4;
  #pragma unroll
  for (int p = 0; p < 4; ++p) {
    const _Float16 h0 = (_Float16)f[2 * p], h1 = (_Float16)f[2 * p + 1];
    h4[p] = (unsigned)__builtin_bit_cast(unsigned short, h0)
          | ((unsigned)__builtin_bit_cast(unsigned short, h1) << 16);
  }
  return __builtin_bit_cast(half8, h4);
}

// 8 floats -> f16 hi + f16 residual frags
__device__ __forceinline__ void cvt8_f16_hilo(const f32x4 a, const f32x4 b,
                                              half8& hi, half8& lo) {
  float f[8];
  *(f32x4*)&f[0] = a;
  *(f32x4*)&f[4] = b;
  u32x4 h4, l4;
  #pragma unroll
  for (int p = 0; p < 4; ++p) {
    const float f0 = f[2 * p], f1 = f[2 * p + 1];
    const _Float16 h0 = (_Float16)f0, h1 = (_Float16)f1;
    const float r0 = f0 - (float)h0, r1 = f1 - (float)h1;
    const _Float16 e0 = (_Float16)r0, e1 = (_Float16)r1;
    h4[p] = (unsigned)__builtin_bit_cast(unsigned short, h0)
          | ((unsigned)__builtin_bit_cast(unsigned short, h1) << 16);
    l4[p] = (unsigned)__builtin_bit_cast(unsigned short, e0)
          | ((unsigned)__builtin_bit_cast(unsigned short, e1) << 16);
  }
  hi = __builtin_bit_cast(half8, h4);
  lo = __builtin_bit_cast(half8, l4);
}

__device__ __forceinline__ unsigned pk2_f16(float a, float b) {
  const _Float16 ha = (_Float16)a, hb = (_Float16)b;
  return (unsigned)__builtin_bit_cast(unsigned short, ha)
       | ((unsigned)__builtin_bit_cast(unsigned short, hb) << 16);
}

// f32x4 -> f16 hi pair-words + f16 residual pair-words
__device__ __forceinline__ void pk4_f16_hilo(const f32x4 v, u32x2& hi, u32x2& lo) {
  const _Float16 h0 = (_Float16)v[0], h1 = (_Float16)v[1];
  const _Float16 h2 = (_Float16)v[2], h3 = (_Float16)v[3];
  const float r0 = v[0] - (float)h0, r1 = v[1] - (float)h1;
  const float r2 = v[2] - (float)h2, r3 = v[3] - (float)h3;
  hi[0] = (unsigned)__builtin_bit_cast(unsigned short, h0)
        | ((unsigned)__builtin_bit_cast(unsigned short, h1) << 16);
  hi[1] = (unsigned)__builtin_bit_cast(unsigned short, h2)
        | ((unsigned)__builtin_bit_cast(unsigned short, h3) << 16);
  lo[0] = pk2_f16(r0, r1);
  lo[1] = pk2_f16(r2, r3);
}

// fast tanh: 1 - 2/(1+exp2(2x*log2e)), copysign. ~6 VALU, ~1e-6 rel err.
__device__ __forceinline__ float ftanh(float x) {
  const float ax = __builtin_fabsf(x);
  const float p  = __builtin_amdgcn_exp2f(ax * 2.8853900817779268f);
  const float r  = __builtin_amdgcn_rcpf(p + 1.0f);
  const float t  = __builtin_fmaf(-2.0f, r, 1.0f);
  return __builtin_copysignf(t, x);
}

#define SCAN_BAR() do { \
    __asm__ volatile("s_waitcnt lgkmcnt(0)" ::: "memory"); \
    __builtin_amdgcn_s_barrier(); \
    __asm__ volatile("" ::: "memory"); } while (0)

// =====================================================================
// Encoder (MFMA): 10240 gathered rows (40 forcing steps x 256 batch),
// 64->128->128 tanh MLP, f16-stationary weights, x in f16 hi+lo.
// Output stashed into zs forcing slots. Grid 160 x 4 waves.
// =====================================================================
constexpr int ENC_NT = 4;

__global__ __launch_bounds__(256, 2) void enc_mfma_kernel(
    const float* __restrict__ x, const float* __restrict__ w1,
    const float* __restrict__ b1v, const float* __restrict__ w2,
    const float* __restrict__ b2v, float* __restrict__ zs)
{
  const int tid = threadIdx.x;
  const int w = tid >> 6, l = tid & 63;
  const int rowf = l & 15;
  const int kg = l >> 4;

  __shared__ unsigned hb[2][16][68];

  half8 W1f[2][2], W2f[2][4];
  #pragma unroll
  for (int tm = 0; tm < 2; ++tm) {
    const int m = (2 * w + tm) * 16 + rowf;
    #pragma unroll
    for (int kt = 0; kt < 2; ++kt) {             // K = 64
      const int k0 = kt * 32 + kg * 8;
      W1f[tm][kt] = cvt8_f16(*(const f32x4*)&w1[m * DXc + k0],
                             *(const f32x4*)&w1[m * DXc + k0 + 4]);
    }
    #pragma unroll
    for (int kt = 0; kt < 4; ++kt) {             // K = 128
      const int k0 = kt * 32 + kg * 8;
      W2f[tm][kt] = cvt8_f16(*(const f32x4*)&w2[m * DZc + k0],
                             *(const f32x4*)&w2[m * DZc + k0 + 4]);
    }
  }
  float b1r[2][4], b2r[2][4];
  #pragma unroll
  for (int tm = 0; tm < 2; ++tm)
    #pragma unroll
    for (int j = 0; j < 4; ++j) {
      b1r[tm][j] = b1v[(2 * w + tm) * 16 + kg * 4 + j];
      b2r[tm][j] = b2v[(2 * w + tm) * 16 + kg * 4 + j];
    }

  for (int it = 0; it < ENC_NT; ++it) {
    const int r = blockIdx.x * (ENC_NT * 16) + it * 16 + rowf;
    const int f = r >> 8, b = r & 255;
    const int t = TAUc * (f + 1);
    const float* xr = x + ((size_t)b * TT + t) * DXc + kg * 8;

    f32x4 aH0 = {b1r[0][0], b1r[0][1], b1r[0][2], b1r[0][3]};
    f32x4 aH1 = {b1r[1][0], b1r[1][1], b1r[1][2], b1r[1][3]};
    f32x4 aL0 = {0.f, 0.f, 0.f, 0.f}, aL1 = {0.f, 0.f, 0.f, 0.f};
    #pragma unroll
    for (int kt = 0; kt < 2; ++kt) {
      half8 xh, xl;
      cvt8_f16_hilo(*(const f32x4*)&xr[kt * 32], *(const f32x4*)&xr[kt * 32 + 4],
                    xh, xl);
      aH0 = __builtin_amdgcn_mfma_f32_16x16x32_f16(W1f[0][kt], xh, aH0, 0, 0, 0);
      aH1 = __builtin_amdgcn_mfma_f32_16x16x32_f16(W1f[1][kt], xh, aH1, 0, 0, 0);
      aL0 = __builtin_amdgcn_mfma_f32_16x16x32_f16(W1f[0][kt], xl, aL0, 0, 0, 0);
      aL1 = __builtin_amdgcn_mfma_f32_16x16x32_f16(W1f[1][kt], xl, aL1, 0, 0, 0);
    }
    {
      u32x2 pk0, pk1;
      pk0[0] = pk2_f16(ftanh(aH0[0] + aL0[0]), ftanh(aH0[1] + aL0[1]));
      pk0[1] = pk2_f16(ftanh(aH0[2] + aL0[2]), ftanh(aH0[3] + aL0[3]));
      pk1[0] = pk2_f16(ftanh(aH1[0] + aL1[0]), ftanh(aH1[1] + aL1[1]));
      pk1[1] = pk2_f16(ftanh(aH1[2] + aL1[2]), ftanh(aH1[3] + aL1[3]));
      *(u32x2*)&hb[it & 1][rowf][(2 * w + 0) * 8 + kg * 2] = pk0;
      *(u32x2*)&hb[it & 1][rowf][(2 * w + 1) * 8 + kg * 2] = pk1;
    }
    SCAN_BAR();

    #pragma unroll
    for (int tm = 0; tm < 2; ++tm) {
      f32x4 a2 = {b2r[tm][0], b2r[tm][1], b2r[tm][2], b2r[tm][3]};
      #pragma unroll
      for (int kt = 0; kt < 4; ++kt) {
        const u32x4 hp = *(const u32x4*)&hb[it & 1][rowf][kt * 16 + kg * 4];
        a2 = __builtin_amdgcn_mfma_f32_16x16x32_f16(W2f[tm][kt],
                 __builtin_bit_cast(half8, hp), a2, 0, 0, 0);
      }
      f32x4 ov;
      #pragma unroll
      for (int j = 0; j < 4; ++j) ov[j] = ftanh(a2[j]);
      *(f32x4*)&zs[((size_t)b * TT + t) * DZc + (2 * w + tm) * 16 + kg * 4] = ov;
    }
  }
}

// =====================================================================
// Fused scan+decoder: 16 batch rows x 41 segments (grid 656, 4 waves).
// Recurrence = validated v5. Decoder fused with 1-step lag, zero extra
// in-loop barriers: decL1 rides the basis phase, decL2 rides the
// recurrence phase. zpk/hbuf/pbuf single-buffered (windows separated
// by bar1/bar2 — verified). Epilogue decodes the final z_seq.
// =====================================================================
__global__ __launch_bounds__(256, 1) void scan_dec_kernel(
    const float* __restrict__ AW, const float* __restrict__ z0,
    const float* __restrict__ hvec, const float* __restrict__ alphas,
    const float* __restrict__ thetas,
    const float* __restrict__ dw1, const float* __restrict__ db1,
    const float* __restrict__ dw2, const float* __restrict__ db2,
    float* __restrict__ zs, float* __restrict__ xp)
{
  const int bid = blockIdx.x;
  const int g = bid & 15;
  const int s = bid >> 4;
  const int t0 = s * TAUc;
  const int nsteps = (s == NSEG - 1) ? (TT - t0) : TAUc;

  const int tid = threadIdx.x;
  const int w = tid >> 6, l = tid & 63;
  const int rowf = l & 15;
  const int kg = l >> 4;

  __shared__ float zbuf[DZc][20];
  __shared__ float meanp[16][4];
  __shared__ unsigned pbuf[16][DZc + 4];   // pitch 132
  __shared__ unsigned zpkh[16][68];
  __shared__ unsigned zpkl[16][68];
  __shared__ unsigned hbuf[16][68];

  short8 Whi[2][4], Wlo[2][4];
  #pragma unroll
  for (int tm = 0; tm < 2; ++tm) {
    const int m = (2 * w + tm) * 16 + rowf;
    #pragma unroll
    for (int kt = 0; kt < 4; ++kt) {
      const int kb = kt * 32 + kg * 8;
      float f[8];
      #pragma unroll
      for (int i = 0; i < 8; ++i) {
        const int k = kb + i;
        f[i] = (k == m) ? 0.f : AW[m * DZc + k];
      }
      pack_hilo8(*(const f32x4*)&f[0], *(const f32x4*)&f[4],
                 Whi[tm][kt], Wlo[tm][kt]);
    }
  }
  float a_d[2][4], h_d[2][4];
  #pragma unroll
  for (int tm = 0; tm < 2; ++tm)
    #pragma unroll
    for (int j = 0; j < 4; ++j) {
      const int comp = (2 * w + tm) * 16 + kg * 4 + j;
      a_d[tm][j] = AW[comp * DZc + comp];
      h_d[tm][j] = hvec[comp];
    }

  half8 D1f[2][4], D2f[4];
  #pragma unroll
  for (int tm = 0; tm < 2; ++tm) {
    const int m = (2 * w + tm) * 16 + rowf;
    #pragma unroll
    for (int kt = 0; kt < 4; ++kt) {
      const int k0 = kt * 32 + kg * 8;
      D1f[tm][kt] = cvt8_f16(*(const f32x4*)&dw1[m * DZc + k0],
                             *(const f32x4*)&dw1[m * DZc + k0 + 4]);
    }
  }
  {
    const int m2 = w * 16 + rowf;
    #pragma unroll
    for (int kt = 0; kt < 4; ++kt) {
      const int k0 = kt * 32 + kg * 8;
      D2f[kt] = cvt8_f16(*(const f32x4*)&dw2[m2 * DZc + k0],
                         *(const f32x4*)&dw2[m2 * DZc + k0 + 4]);
    }
  }
  float d1b[2][4], d2b[4];
  #pragma unroll
  for (int tm = 0; tm < 2; ++tm)
    #pragma unroll
    for (int j = 0; j < 4; ++j)
      d1b[tm][j] = db1[(2 * w + tm) * 16 + kg * 4 + j];
  #pragma unroll
  for (int j = 0; j < 4; ++j)
    d2b[j] = db2[w * 16 + kg * 4 + j];

  const int cb = tid >> 1;
  const int rh = tid & 1;
  float th[DBc], al[DBc];
  #pragma unroll
  for (int d = 0; d < DBc; ++d) {
    th[d] = thetas[cb * DBc + d];
    al[d] = alphas[d];
  }

  const int brow = g * GRP + rowf;
  const size_t zb_row = (size_t)brow * TT * DZc;
  const size_t xp_row = (size_t)brow * TT * DXc;
  f32x4 z[2];
  #pragma unroll
  for (int tm = 0; tm < 2; ++tm) {
    const int comp0 = (2 * w + tm) * 16 + kg * 4;
    if (s == 0) z[tm] = *(const f32x4*)&z0[brow * DZc + comp0];
    else        z[tm] = *(const f32x4*)&zs[zb_row + (size_t)t0 * DZc + comp0];
  }

#define PUB_ZPK() do { \
    _Pragma("unroll") \
    for (int tm = 0; tm < 2; ++tm) { \
      u32x2 zh_, zl_; \
      pk4_f16_hilo(z[tm], zh_, zl_); \
      *(u32x2*)&zpkh[rowf][(2 * w + tm) * 8 + kg * 2] = zh_; \
      *(u32x2*)&zpkl[rowf][(2 * w + tm) * 8 + kg * 2] = zl_; \
    } } while (0)

#define DEC_L1() do { \
    f32x4 dAh = {d1b[0][0], d1b[0][1], d1b[0][2], d1b[0][3]}; \
    f32x4 dBh = {d1b[1][0], d1b[1][1], d1b[1][2], d1b[1][3]}; \
    f32x4 dAl = {0.f, 0.f, 0.f, 0.f}, dBl = {0.f, 0.f, 0.f, 0.f}; \
    _Pragma("unroll") \
    for (int kt = 0; kt < 4; ++kt) { \
      const u32x4 bh = *(const u32x4*)&zpkh[rowf][kt * 16 + kg * 4]; \
      const u32x4 bl = *(const u32x4*)&zpkl[rowf][kt * 16 + kg * 4]; \
      const half8 Bh = __builtin_bit_cast(half8, bh); \
      const half8 Bl = __builtin_bit_cast(half8, bl); \
      dAh = __builtin_amdgcn_mfma_f32_16x16x32_f16(D1f[0][kt], Bh, dAh, 0, 0, 0); \
      dBh = __builtin_amdgcn_mfma_f32_16x16x32_f16(D1f[1][kt], Bh, dBh, 0, 0, 0); \
      dAl = __builtin_amdgcn_mfma_f32_16x16x32_f16(D1f[0][kt], Bl, dAl, 0, 0, 0); \
      dBl = __builtin_amdgcn_mfma_f32_16x16x32_f16(D1f[1][kt], Bl, dBl, 0, 0, 0); \
    } \
    u32x2 pk0, pk1; \
    pk0[0] = pk2_f16(ftanh(dAh[0] + dAl[0]), ftanh(dAh[1] + dAl[1])); \
    pk0[1] = pk2_f16(ftanh(dAh[2] + dAl[2]), ftanh(dAh[3] + dAl[3])); \
    pk1[0] = pk2_f16(ftanh(dBh[0] + dBl[0]), ftanh(dBh[1] + dBl[1])); \
    pk1[1] = pk2_f16(ftanh(dBh[2] + dBl[2]), ftanh(dBh[3] + dBl[3])); \
    *(u32x2*)&hbuf[rowf][(2 * w + 0) * 8 + kg * 2] = pk0; \
    *(u32x2*)&hbuf[rowf][(2 * w + 1) * 8 + kg * 2] = pk1; \
    } while (0)

#define DEC_L2(TD) do { \
    f32x4 a2 = {d2b[0], d2b[1], d2b[2], d2b[3]}; \
    _Pragma("unroll") \
    for (int kt = 0; kt < 4; ++kt) { \
      const u32x4 hp = *(const u32x4*)&hbuf[rowf][kt * 16 + kg * 4]; \
      a2 = __builtin_amdgcn_mfma_f32_16x16x32_f16(D2f[kt], \
               __builtin_bit_cast(half8, hp), a2, 0, 0, 0); \
    } \
    f32x4 ov; \
    _Pragma("unroll") \
    for (int j = 0; j < 4; ++j) ov[j] = ftanh(a2[j]); \
    *(f32x4*)&xp[xp_row + (size_t)(TD) * DXc + w * 16 + kg * 4] = ov; \
    } while (0)

  for (int it = 0; it < nsteps; ++it) {
    const int t = t0 + it;

    // Phase A
    float ssum = ((z[0][0] + z[0][1]) + (z[0][2] + z[0][3]))
               + ((z[1][0] + z[1][1]) + (z[1][2] + z[1][3]));
    ssum += __shfl_xor(ssum, 16, 64);
    ssum += __shfl_xor(ssum, 32, 64);
    if (l < 16) meanp[l][w] = ssum;
    #pragma unroll
    for (int tm = 0; tm < 2; ++tm)
      #pragma unroll
      for (int j = 0; j < 4; ++j)
        zbuf[(2 * w + tm) * 16 + kg * 4 + j][rowf] = z[tm][j];
    PUB_ZPK();
    SCAN_BAR();

    // Phase B: basis + decode-L1 (z_seq[t-1])
    {
      float zr[8], mean[8];
      *(f32x4*)&zr[0] = *(const f32x4*)&zbuf[cb][rh * 8];
      *(f32x4*)&zr[4] = *(const f32x4*)&zbuf[cb][rh * 8 + 4];
      #pragma unroll
      for (int q = 0; q < 8; ++q) {
        const f32x4 mp = *(const f32x4*)&meanp[rh * 8 + q][0];
        mean[q] = ((mp[0] + mp[1]) + (mp[2] + mp[3])) * (1.0f / 128.0f);
      }
      #pragma unroll
      for (int q = 0; q < 8; ++q) {
        const float zc = zr[q] - mean[q];
        float bs = 0.f;
        #pragma unroll
        for (int d = 0; d < DBc; ++d)
          bs = fmaf(al[d], fmaxf(zc + th[d], 0.f), bs);
        const unsigned fb = __float_as_uint(bs);
        const float lof = bs - __uint_as_float(fb & 0xFFFF0000u);
        const unsigned pk = perm_b32(__float_as_uint(lof), fb, 0x07060302u);
        pbuf[rh * 8 + q][cb] = pk;
      }
    }
    if (it > 0) DEC_L1();
    SCAN_BAR();

    // Phase C: decode-L2 + recurrence
    if (it > 0) DEC_L2(t - 1);
    {
      f32x4 acc1[2], acc2[2];
      #pragma unroll
      for (int tm = 0; tm < 2; ++tm)
        #pragma unroll
        for (int j = 0; j < 4; ++j) {
          acc1[tm][j] = fmaf(a_d[tm][j], z[tm][j], h_d[tm][j]);
          acc2[tm][j] = 0.f;
        }
      #pragma unroll
      for (int kt = 0; kt < 4; ++kt) {
        const int cbase = kt * 32 + kg * 8;
        const u32x4 p0 = *(const u32x4*)&pbuf[rowf][cbase];
        const u32x4 p1 = *(const u32x4*)&pbuf[rowf][cbase + 4];
        u32x4 hi4, lo4;
        hi4[0] = perm_b32(p0[1], p0[0], 0x05040100u);
        hi4[1] = perm_b32(p0[3], p0[2], 0x05040100u);
        hi4[2] = perm_b32(p1[1], p1[0], 0x05040100u);
        hi4[3] = perm_b32(p1[3], p1[2], 0x05040100u);
        lo4[0] = perm_b32(p0[1], p0[0], 0x07060302u);
        lo4[1] = perm_b32(p0[3], p0[2], 0x07060302u);
        lo4[2] = perm_b32(p1[1], p1[0], 0x07060302u);
        lo4[3] = perm_b32(p1[3], p1[2], 0x07060302u);
        const short8 Bhi = __builtin_bit_cast(short8, hi4);
        const short8 Blo = __builtin_bit_cast(short8, lo4);
        acc1[0] = __builtin_amdgcn_mfma_f32_16x16x32_bf16(Whi[0][kt], Bhi, acc1[0], 0, 0, 0);
        acc1[1] = __builtin_amdgcn_mfma_f32_16x16x32_bf16(Whi[1][kt], Bhi, acc1[1], 0, 0, 0);
        acc2[0] = __builtin_amdgcn_mfma_f32_16x16x32_bf16(Whi[0][kt], Blo, acc2[0], 0, 0, 0);
        acc2[0] = __builtin_amdgcn_mfma_f32_16x16x32_bf16(Wlo[0][kt], Bhi, acc2[0], 0, 0, 0);
        acc2[1] = __builtin_amdgcn_mfma_f32_16x16x32_bf16(Whi[1][kt], Blo, acc2[1], 0, 0, 0);
        acc2[1] = __builtin_amdgcn_mfma_f32_16x16x32_bf16(Wlo[1][kt], Bhi, acc2[1], 0, 0, 0);
      }
      #pragma unroll
      for (int tm = 0; tm < 2; ++tm) {
        f32x4 zn;
        #pragma unroll
        for (int j = 0; j < 4; ++j) {
          float v = acc1[tm][j] + acc2[tm][j];
          zn[j] = fminf(fmaxf(v, -CLIPV), CLIPV);
        }
        *(f32x4*)&zs[zb_row + (size_t)t * DZc + (2 * w + tm) * 16 + kg * 4] = zn;
        z[tm] = zn;
      }
    }
  }

  // epilogue: decode final z_seq of this segment
  PUB_ZPK();
  SCAN_BAR();
  DEC_L1();
  SCAN_BAR();
  DEC_L2(t0 + nsteps - 1);

#undef PUB_ZPK
#undef DEC_L1
#undef DEC_L2
}

extern "C" void kernel_launch(void* const* d_in, const int* in_sizes, int n_in,
                              void* d_out, int out_size, void* d_ws, size_t ws_size,
                              hipStream_t stream) {
  const float* x      = (const float*)d_in[0];
  const float* z0     = (const float*)d_in[1];
  const float* AW     = (const float*)d_in[2];
  const float* hvec   = (const float*)d_in[3];
  const float* alphas = (const float*)d_in[4];
  const float* thetas = (const float*)d_in[5];
  const float* ew1    = (const float*)d_in[6];
  const float* eb1    = (const float*)d_in[7];
  const float* ew2    = (const float*)d_in[8];
  const float* eb2    = (const float*)d_in[9];
  const float* dw1    = (const float*)d_in[10];
  const float* db1    = (const float*)d_in[11];
  const float* dw2    = (const float*)d_in[12];
  const float* db2    = (const float*)d_in[13];

  float* xp = (float*)d_out;                       // (B,T,DX)
  float* zs = xp + (size_t)BB * TT * DXc;          // (B,T,DZ)

  // 1) MFMA encoder: 40 forcing steps -> stash into zs slots
  hipLaunchKernelGGL(enc_mfma_kernel,
                     dim3(NF * BB / (ENC_NT * 16)), dim3(256), 0, stream,
                     x, ew1, eb1, ew2, eb2, zs);

  // 2) fused scan + decoder
  hipLaunchKernelGGL(scan_dec_kernel, dim3((BB / GRP) * NSEG), dim3(256), 0, stream,
                     AW, z0, hvec, alphas, thetas, dw1, db1, dw2, db2, zs, xp);
}